// Round 3
// baseline (69.741 us; speedup 1.0000x reference)
//
#include <hip/hip_runtime.h>

#define B_N 4096
#define K_N 50
#define D_N 128
#define BLOCK_T 256
#define WAVES_PER_BLOCK 4
#define SAMPLES_PER_BLOCK 2                 // 2 waves share one sample's K range
#define NBLOCKS (B_N / SAMPLES_PER_BLOCK)   // 2048 blocks -> 8192 waves = 32/CU

__global__ __launch_bounds__(BLOCK_T) void disloss_fused(
    const float* __restrict__ emb_batch,    // [B, D]
    const float* __restrict__ embedding,    // [V, D]
    const float* __restrict__ attr_sim,     // [B, K]
    const int*   __restrict__ indices,      // [B, K]
    float*        __restrict__ partials,    // [NBLOCKS]
    unsigned int* __restrict__ counter,     // [1], zeroed each call
    float*        __restrict__ out)         // [1]
{
    const int wave = threadIdx.x >> 6;      // 0..3
    const int lane = threadIdx.x & 63;
    const int half = lane >> 5;             // 0 or 1: which k of the pair
    const int sub  = (lane & 31) * 4;       // float4 slot within the 128-f32 row
    const int s    = wave >> 1;             // sample within block (0..1)
    const int p    = wave & 1;              // which half of the K range
    const int b    = blockIdx.x * SAMPLES_PER_BLOCK + s;

    const float4 eb = *reinterpret_cast<const float4*>(
        &emb_batch[(size_t)b * D_N + sub]);

    const int kbase  = p ? 26 : 0;
    const int npairs = p ? 12 : 13;          // 26 + 24 = 50 k's total

    int   myidx  = 0;
    float myattr = 0.0f;
    if (lane < 2 * npairs) {
        myidx  = indices[(size_t)b * K_N + kbase + lane];
        myattr = attr_sim[(size_t)b * K_N + kbase + lane];
    }

    float acc = 0.0f;
    #pragma unroll 4
    for (int it = 0; it < npairs; ++it) {
        const int   kl  = 2 * it + half;     // lane-half picks k0 or k1
        const int   idx = __shfl(myidx,  kl);
        const float a   = __shfl(myattr, kl);
        const float4 g = *reinterpret_cast<const float4*>(
            &embedding[(size_t)idx * D_N + sub]);
        const float dx = g.x - eb.x;
        const float dy = g.y - eb.y;
        const float dz = g.z - eb.z;
        const float dw = g.w - eb.w;
        acc += a * (dx * dx + dy * dy + dz * dz + dw * dw);
    }

    // Wave reduction (64 lanes)
    #pragma unroll
    for (int off = 32; off > 0; off >>= 1)
        acc += __shfl_down(acc, off);

    __shared__ float smem[WAVES_PER_BLOCK];
    __shared__ int is_last;
    if (lane == 0) smem[wave] = acc;
    __syncthreads();

    if (threadIdx.x == 0) {
        partials[blockIdx.x] = smem[0] + smem[1] + smem[2] + smem[3];
        __threadfence();                      // make partial visible device-wide
        const unsigned int old = atomicAdd(counter, 1u);
        is_last = (old == NBLOCKS - 1) ? 1 : 0;
    }
    __syncthreads();

    if (is_last) {
        __threadfence();                      // acquire: see all partials
        float r = 0.0f;
        #pragma unroll
        for (int i = threadIdx.x; i < NBLOCKS; i += BLOCK_T)
            r += partials[i];
        #pragma unroll
        for (int off = 32; off > 0; off >>= 1)
            r += __shfl_down(r, off);
        __shared__ float smem2[WAVES_PER_BLOCK];
        if (lane == 0) smem2[wave] = r;
        __syncthreads();
        if (threadIdx.x == 0)
            out[0] = (smem2[0] + smem2[1] + smem2[2] + smem2[3]) / (float)B_N;
    }
}

extern "C" void kernel_launch(void* const* d_in, const int* in_sizes, int n_in,
                              void* d_out, int out_size, void* d_ws, size_t ws_size,
                              hipStream_t stream) {
    const float* emb_batch = (const float*)d_in[0];   // [B, D]
    const float* embedding = (const float*)d_in[1];   // [V, D]
    const float* attr_sim  = (const float*)d_in[2];   // [B, K]
    const int*   indices   = (const int*)d_in[3];     // [B, K]
    // d_in[4] = beta (unused by the reference computation)

    float*        out      = (float*)d_out;
    float*        partials = (float*)d_ws;                       // NBLOCKS floats
    unsigned int* counter  = (unsigned int*)((char*)d_ws + NBLOCKS * sizeof(float));

    hipMemsetAsync(counter, 0, sizeof(unsigned int), stream);    // capturable
    disloss_fused<<<NBLOCKS, BLOCK_T, 0, stream>>>(emb_batch, embedding, attr_sim,
                                                   indices, partials, counter, out);
}

// Round 4
// 49.620 us; speedup vs baseline: 1.4055x; 1.4055x over previous
//
#include <hip/hip_runtime.h>

#define B_N 4096
#define K_N 50
#define D_N 128
#define BLOCK_T 256
#define WAVES_PER_BLOCK 4
#define SAMPLES_PER_BLOCK 2                 // 2 waves share one sample's K range
#define NBLOCKS (B_N / SAMPLES_PER_BLOCK)   // 2048 blocks -> 8192 waves = 32/CU

__global__ __launch_bounds__(BLOCK_T) void disloss_fused(
    const float* __restrict__ emb_batch,    // [B, D]
    const float* __restrict__ embedding,    // [V, D]
    const float* __restrict__ attr_sim,     // [B, K]
    const int*   __restrict__ indices,      // [B, K]
    float*       __restrict__ out)          // [1], zeroed each call
{
    const int wave = threadIdx.x >> 6;      // 0..3
    const int lane = threadIdx.x & 63;
    const int half = lane >> 5;             // 0 or 1: which k of the pair
    const int sub  = (lane & 31) * 4;       // float4 slot within the 128-f32 row
    const int s    = wave >> 1;             // sample within block (0..1)
    const int p    = wave & 1;              // which half of the K range
    const int b    = blockIdx.x * SAMPLES_PER_BLOCK + s;

    // Each half-wave covers the full 512 B row: lanes (0..31) and (32..63) read
    // the same emb_batch row, different gathered rows.
    const float4 eb = *reinterpret_cast<const float4*>(
        &emb_batch[(size_t)b * D_N + sub]);

    const int kbase  = p ? 26 : 0;
    const int npairs = p ? 12 : 13;          // 26 + 24 = 50 k's total

    int   myidx  = 0;
    float myattr = 0.0f;
    if (lane < 2 * npairs) {
        myidx  = indices[(size_t)b * K_N + kbase + lane];
        myattr = attr_sim[(size_t)b * K_N + kbase + lane];
    }

    float acc = 0.0f;
    #pragma unroll 4
    for (int it = 0; it < npairs; ++it) {
        const int   kl  = 2 * it + half;     // lane-half picks k0 or k1
        const int   idx = __shfl(myidx,  kl);
        const float a   = __shfl(myattr, kl);
        const float4 g = *reinterpret_cast<const float4*>(
            &embedding[(size_t)idx * D_N + sub]);
        const float dx = g.x - eb.x;
        const float dy = g.y - eb.y;
        const float dz = g.z - eb.z;
        const float dw = g.w - eb.w;
        acc += a * (dx * dx + dy * dy + dz * dz + dw * dw);
    }

    // Wave reduction (64 lanes)
    #pragma unroll
    for (int off = 32; off > 0; off >>= 1)
        acc += __shfl_down(acc, off);

    __shared__ float smem[WAVES_PER_BLOCK];
    if (lane == 0) smem[wave] = acc;
    __syncthreads();

    // One device-scope float atomic per block (coherent, no fence needed).
    // Pre-scaled by 1/B so out accumulates directly to the mean.
    if (threadIdx.x == 0)
        atomicAdd(out, (smem[0] + smem[1] + smem[2] + smem[3]) * (1.0f / B_N));
}

extern "C" void kernel_launch(void* const* d_in, const int* in_sizes, int n_in,
                              void* d_out, int out_size, void* d_ws, size_t ws_size,
                              hipStream_t stream) {
    const float* emb_batch = (const float*)d_in[0];   // [B, D]
    const float* embedding = (const float*)d_in[1];   // [V, D]
    const float* attr_sim  = (const float*)d_in[2];   // [B, K]
    const int*   indices   = (const int*)d_in[3];     // [B, K]
    // d_in[4] = beta (unused by the reference computation)

    float* out = (float*)d_out;

    // Graph replays accumulate into out -> zero it at the head of every call.
    hipMemsetAsync(out, 0, sizeof(float), stream);
    disloss_fused<<<NBLOCKS, BLOCK_T, 0, stream>>>(emb_batch, embedding, attr_sim,
                                                   indices, out);
}

// Round 5
// 27.771 us; speedup vs baseline: 2.5113x; 1.7868x over previous
//
#include <hip/hip_runtime.h>

#define B_N 4096
#define K_N 50
#define D_N 128
#define BLOCK_T 1024
#define WAVES_PER_BLOCK 16                  // 1 sample per wave
#define NBLOCKS (B_N / WAVES_PER_BLOCK)     // 256 blocks -> 16 waves/CU

__global__ __launch_bounds__(BLOCK_T) void disloss_fused(
    const float* __restrict__ emb_batch,    // [B, D]
    const float* __restrict__ embedding,    // [V, D]
    const float* __restrict__ attr_sim,     // [B, K]
    const int*   __restrict__ indices,      // [B, K]
    float*       __restrict__ out)          // [1], zeroed each call
{
    const int wave = threadIdx.x >> 6;      // 0..15
    const int lane = threadIdx.x & 63;
    const int half = lane >> 5;             // 0/1: which k of the gathered pair
    const int sub  = (lane & 31) * 4;       // float4 slot within the 128-f32 row
    const int b    = blockIdx.x * WAVES_PER_BLOCK + wave;

    // Preload this sample's 50 indices + attr weights into lanes 0..49
    int   myidx  = 0;
    float myattr = 0.0f;
    if (lane < K_N) {
        myidx  = indices[(size_t)b * K_N + lane];
        myattr = attr_sim[(size_t)b * K_N + lane];
    }

    // Each half-wave covers the full 512 B row of this sample's embedding.
    const float4 eb = *reinterpret_cast<const float4*>(
        &emb_batch[(size_t)b * D_N + sub]);

    float acc = 0.0f;
    #pragma unroll 5
    for (int it = 0; it < K_N / 2; ++it) {   // 25 iters, 2 rows gathered per iter
        const int   kl  = 2 * it + half;
        const int   idx = __shfl(myidx,  kl);
        const float a   = __shfl(myattr, kl);
        const float4 g = *reinterpret_cast<const float4*>(
            &embedding[(size_t)idx * D_N + sub]);
        const float dx = g.x - eb.x;
        const float dy = g.y - eb.y;
        const float dz = g.z - eb.z;
        const float dw = g.w - eb.w;
        acc += a * (dx * dx + dy * dy + dz * dz + dw * dw);
    }

    // Wave reduction (64 lanes)
    #pragma unroll
    for (int off = 32; off > 0; off >>= 1)
        acc += __shfl_down(acc, off);

    __shared__ float smem[WAVES_PER_BLOCK];
    if (lane == 0) smem[wave] = acc;
    __syncthreads();

    // One atomic per block; only 256 same-address atomics device-wide (~3 us tail).
    if (threadIdx.x == 0) {
        float s = 0.0f;
        #pragma unroll
        for (int w = 0; w < WAVES_PER_BLOCK; ++w) s += smem[w];
        atomicAdd(out, s * (1.0f / B_N));
    }
}

extern "C" void kernel_launch(void* const* d_in, const int* in_sizes, int n_in,
                              void* d_out, int out_size, void* d_ws, size_t ws_size,
                              hipStream_t stream) {
    const float* emb_batch = (const float*)d_in[0];   // [B, D]
    const float* embedding = (const float*)d_in[1];   // [V, D]
    const float* attr_sim  = (const float*)d_in[2];   // [B, K]
    const int*   indices   = (const int*)d_in[3];     // [B, K]
    // d_in[4] = beta (unused by the reference computation)

    float* out = (float*)d_out;

    // Graph replays accumulate into out -> zero it at the head of every call.
    hipMemsetAsync(out, 0, sizeof(float), stream);
    disloss_fused<<<NBLOCKS, BLOCK_T, 0, stream>>>(emb_batch, embedding, attr_sim,
                                                   indices, out);
}

// Round 6
// 23.469 us; speedup vs baseline: 2.9717x; 1.1833x over previous
//
#include <hip/hip_runtime.h>

#define B_N 4096
#define K_N 50
#define D_N 128
#define WAVES_PER_BLOCK 4
#define BLOCK_T 256
#define NBLOCKS (B_N / WAVES_PER_BLOCK)   // 1024
#define RED_T 1024                        // kernel2: one thread per partial

__global__ __launch_bounds__(BLOCK_T) void disloss_main(
    const float* __restrict__ emb_batch,   // [B, D]
    const float* __restrict__ embedding,   // [V, D]
    const float* __restrict__ attr_sim,    // [B, K]
    const int*   __restrict__ indices,     // [B, K]
    float*       __restrict__ partials)    // [NBLOCKS]
{
    const int wave = threadIdx.x >> 6;     // 0..3
    const int lane = threadIdx.x & 63;     // 0..63
    const int b = blockIdx.x * WAVES_PER_BLOCK + wave;

    // This sample's embedding slice: 2 consecutive floats per lane (512 B/wave, coalesced)
    const float2 eb = *reinterpret_cast<const float2*>(&emb_batch[(size_t)b * D_N + lane * 2]);

    // Preload this sample's K indices + attr weights into lanes 0..K-1
    int   myidx  = 0;
    float myattr = 0.0f;
    if (lane < K_N) {
        myidx  = indices[(size_t)b * K_N + lane];
        myattr = attr_sim[(size_t)b * K_N + lane];
    }

    float acc = 0.0f;
    #pragma unroll 10
    for (int k = 0; k < K_N; ++k) {
        const int   idx = __shfl(myidx,  k);
        const float a   = __shfl(myattr, k);
        const float2 g = *reinterpret_cast<const float2*>(
            &embedding[(size_t)idx * D_N + lane * 2]);
        const float dx = g.x - eb.x;
        const float dy = g.y - eb.y;
        acc += a * (dx * dx + dy * dy);
    }

    // Wave reduction (64 lanes)
    #pragma unroll
    for (int off = 32; off > 0; off >>= 1)
        acc += __shfl_down(acc, off);

    __shared__ float s[WAVES_PER_BLOCK];
    if (lane == 0) s[wave] = acc;
    __syncthreads();
    if (threadIdx.x == 0)
        partials[blockIdx.x] = s[0] + s[1] + s[2] + s[3];
}

__global__ __launch_bounds__(RED_T) void disloss_reduce(
    const float* __restrict__ partials,
    float*       __restrict__ out)
{
    // One thread per partial: single global read each, no loop.
    float acc = partials[threadIdx.x];

    #pragma unroll
    for (int off = 32; off > 0; off >>= 1)
        acc += __shfl_down(acc, off);

    __shared__ float s[RED_T / 64];
    const int wave = threadIdx.x >> 6;
    const int lane = threadIdx.x & 63;
    if (lane == 0) s[wave] = acc;
    __syncthreads();
    if (threadIdx.x == 0) {
        float r = 0.0f;
        #pragma unroll
        for (int w = 0; w < RED_T / 64; ++w) r += s[w];
        out[0] = r / (float)B_N;
    }
}

extern "C" void kernel_launch(void* const* d_in, const int* in_sizes, int n_in,
                              void* d_out, int out_size, void* d_ws, size_t ws_size,
                              hipStream_t stream) {
    const float* emb_batch = (const float*)d_in[0];   // [B, D]
    const float* embedding = (const float*)d_in[1];   // [V, D]
    const float* attr_sim  = (const float*)d_in[2];   // [B, K]
    const int*   indices   = (const int*)d_in[3];     // [B, K]
    // d_in[4] = beta (unused by the reference computation)

    float* out      = (float*)d_out;
    float* partials = (float*)d_ws;                   // NBLOCKS floats (4 KB)

    disloss_main<<<NBLOCKS, BLOCK_T, 0, stream>>>(emb_batch, embedding, attr_sim,
                                                  indices, partials);
    disloss_reduce<<<1, RED_T, 0, stream>>>(partials, out);
}